// Round 1
// baseline (221.091 us; speedup 1.0000x reference)
//
#include <hip/hip_runtime.h>

#define NB 512
#define ND 256
#define NKQ 65536
#define LCOLS 65539            // 3 + 65536
#define QTAIL 64000            // 65536 - 1536
#define TEMP 0.07f

// d_out element offsets (f32)
#define OFF_LABELS 33555968ull // 512*65539
#define OFF_SCORE  67111936ull // 2*512*65539
#define OFF_QUEUE  67115520ull // OFF_SCORE + 512*7

typedef __attribute__((ext_vector_type(8))) _Float16 half8;
typedef __attribute__((ext_vector_type(4))) float f32x4;

__device__ inline float wave_sum(float v) {
#pragma unroll
  for (int m = 1; m < 64; m <<= 1) v += __shfl_xor(v, m, 64);
  return v;
}
__device__ inline float wave_max(float v) {
#pragma unroll
  for (int m = 1; m < 64; m <<= 1) v = fmaxf(v, __shfl_xor(v, m, 64));
  return v;
}

// ws layout (bytes):
// [0, 262144)        : fp16 q in MFMA A-fragment order  (512*256*2)
// [262144, 786432)   : f32 normalized q                 (512*256*4)
// [786432, 788480)   : pos_min[512]
// [788480, 794624)   : score_pos[512*3]

// rows 0..511: normalize query -> ws (f32 + fp16 frag layout)
// rows 512..2047: normalize key_emb -> new_queue tail
__global__ __launch_bounds__(64) void knorm(const float* __restrict__ query,
                                            const float* __restrict__ key_emb,
                                            float* __restrict__ out,
                                            _Float16* __restrict__ qfrag,
                                            float* __restrict__ qf32) {
  int r = blockIdx.x;
  int l = threadIdx.x;
  const float* src = (r < NB) ? (query + (size_t)r * ND) : (key_emb + (size_t)(r - NB) * ND);
  float x0 = src[l], x1 = src[l + 64], x2 = src[l + 128], x3 = src[l + 192];
  float ss = wave_sum(x0 * x0 + x1 * x1 + x2 * x2 + x3 * x3);
  float sc = 1.0f / fmaxf(sqrtf(ss), 1e-12f);
  x0 *= sc; x1 *= sc; x2 *= sc; x3 *= sc;
  if (r < NB) {
    float xs[4] = {x0, x1, x2, x3};
#pragma unroll
    for (int i = 0; i < 4; i++) {
      int d = l + i * 64;
      qf32[r * ND + d] = xs[i];
      // A-frag layout for mfma_f32_16x16x32: lane (g<<4)|rr holds A[rr][kk*32+g*8+j]
      int mt = r >> 4, rr = r & 15, kk = d >> 5, g = (d >> 3) & 3, j = d & 7;
      int lane = (g << 4) | rr;
      qfrag[((mt * 8 + kk) * 64 + lane) * 8 + j] = (_Float16)xs[i];
    }
  } else {
    int i2 = r - NB;
    float* dst = out + OFF_QUEUE + (size_t)(QTAIL + i2) * ND;
    dst[l] = x0; dst[l + 64] = x1; dst[l + 128] = x2; dst[l + 192] = x3;
  }
}

// per-row positive scores (f32 exact), logits/labels/score pos part, pos_min
__global__ __launch_bounds__(64) void kpos(const float* __restrict__ qf32,
                                           float* __restrict__ out,
                                           float* __restrict__ posmin,
                                           float* __restrict__ spos) {
  int b = blockIdx.x, l = threadIdx.x;
  const float* q = qf32 + (size_t)b * ND;
  float q0 = q[l], q1 = q[l + 64], q2 = q[l + 128], q3 = q[l + 192];
  const float* kbase = out + OFF_QUEUE + (size_t)(QTAIL + b * 3) * ND;
  float sp[3];
#pragma unroll
  for (int j = 0; j < 3; j++) {
    const float* kp = kbase + (size_t)j * ND;
    float p = q0 * kp[l] + q1 * kp[l + 64] + q2 * kp[l + 128] + q3 * kp[l + 192];
    sp[j] = wave_sum(p);
  }
  if (l == 0) {
    float* lg = out + (size_t)b * LCOLS;
    float* lb = out + OFF_LABELS + (size_t)b * LCOLS;
    float* scr = out + OFF_SCORE + (size_t)b * 7;
#pragma unroll
    for (int j = 0; j < 3; j++) {
      lg[j] = sp[j] / TEMP;
      lb[j] = 1.0f;
      scr[4 + j] = sp[j];
      spos[b * 3 + j] = sp[j];
    }
    posmin[b] = fminf(sp[0], fminf(sp[1], sp[2]));
  }
}

// main: block owns 64 queue rows (N), loops all 512 q rows (M).
// Fuses: queue->fp16 LDS staging, FIFO copy to new_queue, logits + labels writes.
__global__ __launch_bounds__(256) void kgemm(const float* __restrict__ queue,
                                             const _Float16* __restrict__ qfrag,
                                             float* __restrict__ out) {
  __shared__ char tileb[64 * 512];  // 64 rows x 256 fp16, XOR-swizzled
  int nbase = blockIdx.x * 64;
  int tid = threadIdx.x;
  const float4* qp = (const float4*)queue;
  float4* nq = (float4*)(out + OFF_QUEUE);
#pragma unroll
  for (int i = 0; i < 16; i++) {
    int idx = tid + i * 256;          // 0..4095 = 64 rows * 64 float4
    int row = idx >> 6, c4 = idx & 63;
    int grow = nbase + row;
    float4 v = qp[(size_t)grow * 64 + c4];
    if (grow >= 1536) nq[(size_t)(grow - 1536) * 64 + c4] = v;  // fused FIFO copy
    union { uint2 u; _Float16 h[4]; } pk;
    pk.h[0] = (_Float16)v.x; pk.h[1] = (_Float16)v.y;
    pk.h[2] = (_Float16)v.z; pk.h[3] = (_Float16)v.w;
    int boff = row * 512 + ((c4 * 8) ^ ((row & 7) << 4));
    *(uint2*)(tileb + boff) = pk.u;
  }
  __syncthreads();

  int w = tid >> 6, l = tid & 63;
  int r = l & 15, g4 = l >> 4;
  int brow = w * 16 + r;              // this lane's n within the 64-col tile
  // B fragments held in registers: LDS tile read exactly once per wave
  uint4 bf[8];
#pragma unroll
  for (int kk = 0; kk < 8; kk++) {
    int boff = brow * 512 + (((kk * 64 + g4 * 16)) ^ ((brow & 7) << 4));
    bf[kk] = *(const uint4*)(tileb + boff);
  }
  const uint4* ap = (const uint4*)qfrag;
  int ncol = 3 + nbase + brow;
  float* lg = out;
  float* lb = out + OFF_LABELS;
#pragma unroll 2
  for (int mt = 0; mt < 32; mt++) {
    uint4 af[8];
#pragma unroll
    for (int kk = 0; kk < 8; kk++) af[kk] = ap[(mt * 8 + kk) * 64 + l];
    f32x4 acc = {0.f, 0.f, 0.f, 0.f};
#pragma unroll
    for (int kk = 0; kk < 8; kk++)
      acc = __builtin_amdgcn_mfma_f32_16x16x32_f16(
          __builtin_bit_cast(half8, af[kk]),
          __builtin_bit_cast(half8, bf[kk]), acc, 0, 0, 0);
    int row0 = mt * 16 + g4 * 4;  // D: col = lane&15, row = (lane>>4)*4 + j
#pragma unroll
    for (int j = 0; j < 4; j++) {
      int o = (row0 + j) * LCOLS + ncol;
      lg[o] = acc[j] * (1.0f / TEMP);
      lb[o] = 1.0f;
    }
  }
}

// second pass over logits rows: per-row sum/sumsq/max/count -> score[:,0:4]
__global__ __launch_bounds__(256) void kstat(float* __restrict__ out,
                                             const float* __restrict__ posmin,
                                             const float* __restrict__ spos) {
  int b = blockIdx.x, tid = threadIdx.x;
  const float* row = out + (size_t)b * LCOLS + 3;
  float pm = posmin[b];
  float s = 0.f, s2 = 0.f, mx = -2.f;
  int cnt = 0;
  for (int c = tid; c < NKQ; c += 256) {
    float v = row[c] * TEMP;  // recover score_neg from logits
    s += v; s2 += v * v; mx = fmaxf(mx, v);
    cnt += (v > pm) ? 1 : 0;
  }
  float cf = (float)cnt;
  s = wave_sum(s); s2 = wave_sum(s2); cf = wave_sum(cf); mx = wave_max(mx);
  __shared__ float red[4][4];
  int w = tid >> 6, l = tid & 63;
  if (l == 0) { red[w][0] = s; red[w][1] = s2; red[w][2] = cf; red[w][3] = mx; }
  __syncthreads();
  if (tid == 0) {
    float S = 0, S2 = 0, C = 0, M = -2.f;
    for (int i = 0; i < 4; i++) {
      S += red[i][0]; S2 += red[i][1]; C += red[i][2]; M = fmaxf(M, red[i][3]);
    }
    float mean = S / (float)NKQ;
    float var = (S2 - S * S / (float)NKQ) / (float)(NKQ - 1);  // ddof=1
    float cp = 0.f;
    for (int j = 0; j < 3; j++) cp += (M > spos[b * 3 + j]) ? 1.f : 0.f;
    float* scr = out + OFF_SCORE + (size_t)b * 7;
    scr[0] = mean; scr[1] = var; scr[2] = C; scr[3] = cp;
  }
}

extern "C" void kernel_launch(void* const* d_in, const int* in_sizes, int n_in,
                              void* d_out, int out_size, void* d_ws, size_t ws_size,
                              hipStream_t stream) {
  const float* query = (const float*)d_in[0];
  const float* key_emb = (const float*)d_in[1];
  const float* queue = (const float*)d_in[2];
  float* out = (float*)d_out;
  _Float16* qfrag = (_Float16*)d_ws;
  float* qf32 = (float*)((char*)d_ws + 262144);
  float* posmin = (float*)((char*)d_ws + 786432);
  float* spos = (float*)((char*)d_ws + 788480);

  knorm<<<2048, 64, 0, stream>>>(query, key_emb, out, qfrag, qf32);
  kpos<<<512, 64, 0, stream>>>(qf32, out, posmin, spos);
  kgemm<<<1024, 256, 0, stream>>>(queue, qfrag, out);
  kstat<<<512, 256, 0, stream>>>(out, posmin, spos);
}

// Round 3
// 177.494 us; speedup vs baseline: 1.2456x; 1.2456x over previous
//
#include <hip/hip_runtime.h>

#define NB 512
#define ND 256
#define NKQ 65536
#define LCOLS 65539            // 3 + 65536
#define QTAIL 64000            // 65536 - 1536
#define TEMP 0.07f

// d_out element offsets (f32)
#define OFF_LABELS 33555968ull // 512*65539
#define OFF_SCORE  67111936ull // 2*512*65539
#define OFF_QUEUE  67115520ull // OFF_SCORE + 512*7

typedef __attribute__((ext_vector_type(8))) _Float16 half8;
typedef __attribute__((ext_vector_type(4))) float f32x4;

__device__ inline float wave_sum(float v) {
#pragma unroll
  for (int m = 1; m < 64; m <<= 1) v += __shfl_xor(v, m, 64);
  return v;
}

// ws layout (bytes):
// [0, 262144)          : fp16 normalized q, row-major [512][256]
// [262144, 786432)     : f32 normalized q
// [786432, 788480)     : pos_min[512]
// [788480, 794624)     : score_pos[512*3]
// [1048576, 9437184)   : stat partials [512 rows][1024 blocks][4] f32

// blocks 0..511: normalize 4 rows each (query -> ws, key_emb -> queue tail)
// blocks 512..2047: fill labels region with 1.0f (contiguous, 16B-aligned)
__global__ __launch_bounds__(256) void kprep(const float* __restrict__ query,
                                             const float* __restrict__ key_emb,
                                             float* __restrict__ out,
                                             _Float16* __restrict__ qf16,
                                             float* __restrict__ qf32) {
  int blk = blockIdx.x;
  if (blk < 512) {
    int w = threadIdx.x >> 6, l = threadIdx.x & 63;
    int r = blk * 4 + w;  // 0..2047
    const float* src = (r < NB) ? (query + (size_t)r * ND)
                                : (key_emb + (size_t)(r - NB) * ND);
    float x0 = src[l], x1 = src[l + 64], x2 = src[l + 128], x3 = src[l + 192];
    float ss = wave_sum(x0 * x0 + x1 * x1 + x2 * x2 + x3 * x3);
    float sc = 1.0f / fmaxf(sqrtf(ss), 1e-12f);
    x0 *= sc; x1 *= sc; x2 *= sc; x3 *= sc;
    if (r < NB) {
      float xs[4] = {x0, x1, x2, x3};
#pragma unroll
      for (int i = 0; i < 4; i++) {
        int d = l + i * 64;
        qf32[r * ND + d] = xs[i];
        qf16[r * ND + d] = (_Float16)xs[i];
      }
    } else {
      float* dst = out + OFF_QUEUE + (size_t)(QTAIL + r - NB) * ND;
      dst[l] = x0; dst[l + 64] = x1; dst[l + 128] = x2; dst[l + 192] = x3;
    }
  } else {
    // labels = ones over the whole [512][65539] region, flat f32x4 fill
    f32x4 one = {1.f, 1.f, 1.f, 1.f};
    f32x4* lb = (f32x4*)(out + OFF_LABELS);
    const long total4 = (long)NB * LCOLS / 4;  // 8388992
    long stride = (long)(2048 - 512) * 256;
    for (long i = (long)(blk - 512) * 256 + threadIdx.x; i < total4; i += stride)
      __builtin_nontemporal_store(one, lb + i);
  }
}

// per-row positive scores (f32 exact): logits[:, :3], score[:, 4:7], pos_min
__global__ __launch_bounds__(64) void kpos(const float* __restrict__ qf32,
                                           float* __restrict__ out,
                                           float* __restrict__ posmin,
                                           float* __restrict__ spos) {
  int b = blockIdx.x, l = threadIdx.x;
  const float* q = qf32 + (size_t)b * ND;
  float q0 = q[l], q1 = q[l + 64], q2 = q[l + 128], q3 = q[l + 192];
  const float* kbase = out + OFF_QUEUE + (size_t)(QTAIL + b * 3) * ND;
  float sp[3];
#pragma unroll
  for (int j = 0; j < 3; j++) {
    const float* kp = kbase + (size_t)j * ND;
    float p = q0 * kp[l] + q1 * kp[l + 64] + q2 * kp[l + 128] + q3 * kp[l + 192];
    sp[j] = wave_sum(p);
  }
  if (l == 0) {
    float* lg = out + (size_t)b * LCOLS;
    float* scr = out + OFF_SCORE + (size_t)b * 7;
#pragma unroll
    for (int j = 0; j < 3; j++) {
      lg[j] = sp[j] / TEMP;
      scr[4 + j] = sp[j];
      spos[b * 3 + j] = sp[j];
    }
    posmin[b] = fminf(sp[0], fminf(sp[1], sp[2]));
  }
}

// main GEMM: block owns 64 queue cols (N), loops all 512 q rows.
// Fuses: queue->fp16 LDS staging, FIFO copy, coalesced logits writes via LDS
// out-tile, per-row stats partials over this block's 64 cols.
__global__ __launch_bounds__(256) void kgemm(const float* __restrict__ queue,
                                             const _Float16* __restrict__ qf16,
                                             const float* __restrict__ posmin,
                                             float* __restrict__ out,
                                             float* __restrict__ partials) {
  __shared__ uint4 tileb4[64 * 512 / 16];  // 64 rows x 256 fp16, XOR-swizzled
  __shared__ __align__(16) float otile[16 * 68];  // 16 rows x 64 cols, pad 68
  char* tileb = (char*)tileb4;
  int nbase = blockIdx.x * 64;
  int tid = threadIdx.x;
  const f32x4* qp = (const f32x4*)queue;
  f32x4* nq = (f32x4*)(out + OFF_QUEUE);
#pragma unroll
  for (int i = 0; i < 16; i++) {
    int idx = tid + i * 256;          // 64 rows * 64 float4
    int row = idx >> 6, c4 = idx & 63;
    int grow = nbase + row;
    f32x4 v = qp[(size_t)grow * 64 + c4];
    if (grow >= 1536)
      __builtin_nontemporal_store(v, nq + (size_t)(grow - 1536) * 64 + c4);
    union { uint2 u; _Float16 h[4]; } pk;
    pk.h[0] = (_Float16)v.x; pk.h[1] = (_Float16)v.y;
    pk.h[2] = (_Float16)v.z; pk.h[3] = (_Float16)v.w;
    int boff = row * 512 + ((c4 * 8) ^ ((row & 7) << 4));
    *(uint2*)(tileb + boff) = pk.u;
  }
  __syncthreads();

  int w = tid >> 6, l = tid & 63;
  int r = l & 15, g4 = l >> 4;
  int brow = w * 16 + r;              // lane's n within the 64-col tile
  uint4 bf[8];                        // B fragments: LDS tile read exactly once
#pragma unroll
  for (int kk = 0; kk < 8; kk++) {
    int boff = brow * 512 + ((kk * 64 + g4 * 16) ^ ((brow & 7) << 4));
    bf[kk] = *(const uint4*)(tileb + boff);
  }
  const uint4* ap = (const uint4*)qf16;  // row-major: uint4 idx = row*32 + kk*4 + g4
  float* lg = out;
  const float inv_t = 1.0f / TEMP;
  int srow = w * 4 + g4;              // stats row within 16-row tile
  int scol = r * 4;                   // stats col base

#pragma unroll 2
  for (int mt = 0; mt < 32; mt++) {
    uint4 af[8];
#pragma unroll
    for (int kk = 0; kk < 8; kk++)
      af[kk] = ap[(mt * 16 + r) * 32 + kk * 4 + g4];
    f32x4 acc = {0.f, 0.f, 0.f, 0.f};
#pragma unroll
    for (int kk = 0; kk < 8; kk++)
      acc = __builtin_amdgcn_mfma_f32_16x16x32_f16(
          __builtin_bit_cast(half8, af[kk]),
          __builtin_bit_cast(half8, bf[kk]), acc, 0, 0, 0);
    __syncthreads();  // prev iteration's otile readers done
    // D layout: col = lane&15 (= r -> our n), row = (lane>>4)*4 + j
#pragma unroll
    for (int j = 0; j < 4; j++)
      otile[(g4 * 4 + j) * 68 + w * 16 + r] = acc[j];
    __syncthreads();
    // coalesced logits write: 64 consecutive floats per 64 lanes
#pragma unroll
    for (int i = 0; i < 4; i++) {
      int idx = tid + i * 256;
      int orow = idx >> 6, ocol = idx & 63;
      float v = otile[orow * 68 + ocol];
      __builtin_nontemporal_store(
          v * inv_t, lg + (size_t)(mt * 16 + orow) * LCOLS + 3 + nbase + ocol);
    }
    // stats over this block's 64 cols: wave w reduces rows w*4..w*4+3
    const f32x4 sv = *(const f32x4*)&otile[srow * 68 + scol];
    float pm = posmin[mt * 16 + srow];
    float s = sv.x + sv.y + sv.z + sv.w;
    float s2 = sv.x * sv.x + sv.y * sv.y + sv.z * sv.z + sv.w * sv.w;
    float mx = fmaxf(fmaxf(sv.x, sv.y), fmaxf(sv.z, sv.w));
    float c = (sv.x > pm ? 1.f : 0.f) + (sv.y > pm ? 1.f : 0.f) +
              (sv.z > pm ? 1.f : 0.f) + (sv.w > pm ? 1.f : 0.f);
#pragma unroll
    for (int m = 1; m < 16; m <<= 1) {
      s += __shfl_xor(s, m, 64);
      s2 += __shfl_xor(s2, m, 64);
      c += __shfl_xor(c, m, 64);
      mx = fmaxf(mx, __shfl_xor(mx, m, 64));
    }
    if ((l & 15) == 0) {
      f32x4 p = {s, s2, mx, c};
      *(f32x4*)&partials[((size_t)(mt * 16 + srow) * 1024 + blockIdx.x) * 4] = p;
    }
  }
}

// combine 1024 per-block partials per row -> score[:, 0:4]
__global__ __launch_bounds__(256) void kreduce(const float* __restrict__ partials,
                                               const float* __restrict__ spos,
                                               float* __restrict__ out) {
  int b = blockIdx.x, tid = threadIdx.x;
  const f32x4* p = (const f32x4*)(partials + (size_t)b * 4096);
  float s = 0.f, s2 = 0.f, mx = -2.f, c = 0.f;
#pragma unroll
  for (int i = 0; i < 4; i++) {
    f32x4 v = p[tid + i * 256];
    s += v.x; s2 += v.y; mx = fmaxf(mx, v.z); c += v.w;
  }
#pragma unroll
  for (int m = 1; m < 64; m <<= 1) {
    s += __shfl_xor(s, m, 64);
    s2 += __shfl_xor(s2, m, 64);
    c += __shfl_xor(c, m, 64);
    mx = fmaxf(mx, __shfl_xor(mx, m, 64));
  }
  __shared__ float red[4][4];
  int w = tid >> 6, l = tid & 63;
  if (l == 0) { red[w][0] = s; red[w][1] = s2; red[w][2] = c; red[w][3] = mx; }
  __syncthreads();
  if (tid == 0) {
    float S = 0, S2 = 0, C = 0, M = -2.f;
    for (int i = 0; i < 4; i++) {
      S += red[i][0]; S2 += red[i][1]; C += red[i][2]; M = fmaxf(M, red[i][3]);
    }
    float mean = S / (float)NKQ;
    float var = (S2 - S * S / (float)NKQ) / (float)(NKQ - 1);  // ddof=1
    float cp = 0.f;
    for (int j = 0; j < 3; j++) cp += (M > spos[b * 3 + j]) ? 1.f : 0.f;
    float* scr = out + OFF_SCORE + (size_t)b * 7;
    scr[0] = mean; scr[1] = var; scr[2] = C; scr[3] = cp;
  }
}

extern "C" void kernel_launch(void* const* d_in, const int* in_sizes, int n_in,
                              void* d_out, int out_size, void* d_ws, size_t ws_size,
                              hipStream_t stream) {
  const float* query = (const float*)d_in[0];
  const float* key_emb = (const float*)d_in[1];
  const float* queue = (const float*)d_in[2];
  float* out = (float*)d_out;
  _Float16* qf16 = (_Float16*)d_ws;
  float* qf32 = (float*)((char*)d_ws + 262144);
  float* posmin = (float*)((char*)d_ws + 786432);
  float* spos = (float*)((char*)d_ws + 788480);
  float* partials = (float*)((char*)d_ws + 1048576);

  kprep<<<2048, 256, 0, stream>>>(query, key_emb, out, qf16, qf32);
  kpos<<<512, 64, 0, stream>>>(qf32, out, posmin, spos);
  kgemm<<<1024, 256, 0, stream>>>(queue, qf16, posmin, out, partials);
  kreduce<<<512, 256, 0, stream>>>(partials, spos, out);
}

// Round 4
// 131.775 us; speedup vs baseline: 1.6778x; 1.3469x over previous
//
#include <hip/hip_runtime.h>

#define NB 512
#define ND 256
#define NKQ 65536
#define LCOLS 65539            // 3 + 65536
#define QTAIL 64000            // 65536 - 1536
#define TEMP 0.07f

// d_out element offsets (f32)
#define OFF_LABELS 33555968ull // 512*65539
#define OFF_SCORE  67111936ull // 2*512*65539
#define OFF_QUEUE  67115520ull // OFF_SCORE + 512*7

typedef __attribute__((ext_vector_type(8))) _Float16 half8;
typedef __attribute__((ext_vector_type(4))) float f32x4;

__device__ inline float wave_sum(float v) {
#pragma unroll
  for (int m = 1; m < 64; m <<= 1) v += __shfl_xor(v, m, 64);
  return v;
}

// ws layout (bytes):
// [0, 262144)          : fp16 normalized q, row-major [512][256]
// [262144, 786432)     : f32 normalized q
// [786432, 788480)     : pos_min[512]
// [788480, 794624)     : score_pos[512*3]
// [1048576, 5242880)   : stat partials [512 rows][512 blocks][4] f32

// blocks 0..511: normalize 4 rows each (query -> ws, key_emb -> queue tail)
// blocks 512..2047: fill labels region with 1.0f (contiguous, 16B-aligned)
__global__ __launch_bounds__(256) void kprep(const float* __restrict__ query,
                                             const float* __restrict__ key_emb,
                                             float* __restrict__ out,
                                             _Float16* __restrict__ qf16,
                                             float* __restrict__ qf32) {
  int blk = blockIdx.x;
  if (blk < 512) {
    int w = threadIdx.x >> 6, l = threadIdx.x & 63;
    int r = blk * 4 + w;  // 0..2047
    const float* src = (r < NB) ? (query + (size_t)r * ND)
                                : (key_emb + (size_t)(r - NB) * ND);
    float x0 = src[l], x1 = src[l + 64], x2 = src[l + 128], x3 = src[l + 192];
    float ss = wave_sum(x0 * x0 + x1 * x1 + x2 * x2 + x3 * x3);
    float sc = 1.0f / fmaxf(sqrtf(ss), 1e-12f);
    x0 *= sc; x1 *= sc; x2 *= sc; x3 *= sc;
    if (r < NB) {
      float xs[4] = {x0, x1, x2, x3};
#pragma unroll
      for (int i = 0; i < 4; i++) {
        int d = l + i * 64;
        qf32[r * ND + d] = xs[i];
        qf16[r * ND + d] = (_Float16)xs[i];
      }
    } else {
      float* dst = out + OFF_QUEUE + (size_t)(QTAIL + r - NB) * ND;
      dst[l] = x0; dst[l + 64] = x1; dst[l + 128] = x2; dst[l + 192] = x3;
    }
  } else {
    // labels = ones over the whole [512][65539] region, flat f32x4 fill
    f32x4 one = {1.f, 1.f, 1.f, 1.f};
    f32x4* lb = (f32x4*)(out + OFF_LABELS);
    const long total4 = (long)NB * LCOLS / 4;  // 8388992
    long stride = (long)(2048 - 512) * 256;
    for (long i = (long)(blk - 512) * 256 + threadIdx.x; i < total4; i += stride)
      __builtin_nontemporal_store(one, lb + i);
  }
}

// per-row positive scores (f32 exact): logits[:, :3], score[:, 4:7], pos_min
__global__ __launch_bounds__(64) void kpos(const float* __restrict__ qf32,
                                           float* __restrict__ out,
                                           float* __restrict__ posmin,
                                           float* __restrict__ spos) {
  int b = blockIdx.x, l = threadIdx.x;
  const float* q = qf32 + (size_t)b * ND;
  float q0 = q[l], q1 = q[l + 64], q2 = q[l + 128], q3 = q[l + 192];
  const float* kbase = out + OFF_QUEUE + (size_t)(QTAIL + b * 3) * ND;
  float sp[3];
#pragma unroll
  for (int j = 0; j < 3; j++) {
    const float* kp = kbase + (size_t)j * ND;
    float p = q0 * kp[l] + q1 * kp[l + 64] + q2 * kp[l + 128] + q3 * kp[l + 192];
    sp[j] = wave_sum(p);
  }
  if (l == 0) {
    float* lg = out + (size_t)b * LCOLS;
    float* scr = out + OFF_SCORE + (size_t)b * 7;
#pragma unroll
    for (int j = 0; j < 3; j++) {
      lg[j] = sp[j] / TEMP;
      scr[4 + j] = sp[j];
      spos[b * 3 + j] = sp[j];
    }
    posmin[b] = fminf(sp[0], fminf(sp[1], sp[2]));
  }
}

// main GEMM: block owns 128 queue cols, loops all 512 q rows.
// No B-LDS: each wave holds its 32 cols' B fragments in registers (built from
// L2-hot queue after the fused FIFO copy). Per-iteration: dbuf A loads,
// 16 MFMA, otile staging, coalesced 512B logits row-segments, stats partials.
__global__ __launch_bounds__(256) void kgemm(const float* __restrict__ queue,
                                             const _Float16* __restrict__ qf16,
                                             const float* __restrict__ posmin,
                                             float* __restrict__ out,
                                             float* __restrict__ partials) {
  __shared__ __align__(16) float otile[16 * 132];  // 16 rows x 128 cols, pad 132
  // XCD swizzle: adjacent column-blocks land on the same XCD L2 (512 % 8 == 0)
  int blk = ((int)blockIdx.x & 7) * 64 + ((int)blockIdx.x >> 3);
  int nbase = blk * 128;
  int tid = threadIdx.x;

  // Phase 0: fused FIFO copy of this block's 128 queue rows (also warms L2)
  const f32x4* qp = (const f32x4*)queue;
  f32x4* nq = (f32x4*)(out + OFF_QUEUE);
#pragma unroll
  for (int i = 0; i < 32; i++) {
    int idx = tid + i * 256;          // 128 rows * 64 f32x4
    int row = idx >> 6, c4 = idx & 63;
    int grow = nbase + row;
    f32x4 v = qp[(size_t)grow * 64 + c4];
    if (grow >= 1536)
      __builtin_nontemporal_store(v, nq + (size_t)(grow - 1536) * 64 + c4);
  }

  // Phase 1: build per-wave B fragments in registers (32 cols per wave)
  int w = tid >> 6, l = tid & 63;
  int r = l & 15, g4 = l >> 4;
  uint4 bf0[8], bf1[8];
  {
    const float* qrow0 = queue + (size_t)(nbase + w * 32 + r) * ND;
    const float* qrow1 = qrow0 + 16 * ND;
#pragma unroll
    for (int kk = 0; kk < 8; kk++) {
      int k0 = kk * 32 + g4 * 8;
      f32x4 a0 = *(const f32x4*)(qrow0 + k0);
      f32x4 a1 = *(const f32x4*)(qrow0 + k0 + 4);
      f32x4 b0 = *(const f32x4*)(qrow1 + k0);
      f32x4 b1 = *(const f32x4*)(qrow1 + k0 + 4);
      half8 h0, h1;
      h0[0] = (_Float16)a0.x; h0[1] = (_Float16)a0.y; h0[2] = (_Float16)a0.z;
      h0[3] = (_Float16)a0.w; h0[4] = (_Float16)a1.x; h0[5] = (_Float16)a1.y;
      h0[6] = (_Float16)a1.z; h0[7] = (_Float16)a1.w;
      h1[0] = (_Float16)b0.x; h1[1] = (_Float16)b0.y; h1[2] = (_Float16)b0.z;
      h1[3] = (_Float16)b0.w; h1[4] = (_Float16)b1.x; h1[5] = (_Float16)b1.y;
      h1[6] = (_Float16)b1.z; h1[7] = (_Float16)b1.w;
      bf0[kk] = __builtin_bit_cast(uint4, h0);
      bf1[kk] = __builtin_bit_cast(uint4, h1);
    }
  }

  const uint4* ap = (const uint4*)qf16;  // row-major: idx = row*32 + kk*4 + g4
  float* lg = out;
  const float inv_t = 1.0f / TEMP;
  int srow = tid >> 4, sc = (tid & 15) * 8;

  auto load_af = [&](uint4* dst, int mtv) {
#pragma unroll
    for (int kk = 0; kk < 8; kk++)
      dst[kk] = ap[(size_t)(mtv * 16 + r) * 32 + kk * 4 + g4];
  };

  auto body = [&](const uint4* af, int mt) {
    f32x4 acc0 = {0.f, 0.f, 0.f, 0.f}, acc1 = {0.f, 0.f, 0.f, 0.f};
#pragma unroll
    for (int kk = 0; kk < 8; kk++) {
      acc0 = __builtin_amdgcn_mfma_f32_16x16x32_f16(
          __builtin_bit_cast(half8, af[kk]), __builtin_bit_cast(half8, bf0[kk]),
          acc0, 0, 0, 0);
      acc1 = __builtin_amdgcn_mfma_f32_16x16x32_f16(
          __builtin_bit_cast(half8, af[kk]), __builtin_bit_cast(half8, bf1[kk]),
          acc1, 0, 0, 0);
    }
    __syncthreads();  // previous iteration's otile readers done
    // D layout: col = lane&15 (our n), row = (lane>>4)*4 + j
#pragma unroll
    for (int j = 0; j < 4; j++) {
      otile[(g4 * 4 + j) * 132 + w * 32 + r] = acc0[j];
      otile[(g4 * 4 + j) * 132 + w * 32 + 16 + r] = acc1[j];
    }
    __syncthreads();
    // logits: 16 rows x 128 cols; each wave-instr writes 512B... (2 waves/row)
#pragma unroll
    for (int i = 0; i < 8; i++) {
      int idx = tid + i * 256;
      int orow = idx >> 7, ocol = idx & 127;
      float v = otile[orow * 132 + ocol];
      lg[(size_t)(mt * 16 + orow) * LCOLS + 3 + nbase + ocol] = v * inv_t;
    }
    // stats: 16 lanes per row, 8 cols per lane
    f32x4 s0 = *(const f32x4*)&otile[srow * 132 + sc];
    f32x4 s1 = *(const f32x4*)&otile[srow * 132 + sc + 4];
    float pm = posmin[mt * 16 + srow];
    float s = s0.x + s0.y + s0.z + s0.w + s1.x + s1.y + s1.z + s1.w;
    float s2 = s0.x * s0.x + s0.y * s0.y + s0.z * s0.z + s0.w * s0.w +
               s1.x * s1.x + s1.y * s1.y + s1.z * s1.z + s1.w * s1.w;
    float mx = fmaxf(fmaxf(fmaxf(s0.x, s0.y), fmaxf(s0.z, s0.w)),
                     fmaxf(fmaxf(s1.x, s1.y), fmaxf(s1.z, s1.w)));
    float c = (s0.x > pm ? 1.f : 0.f) + (s0.y > pm ? 1.f : 0.f) +
              (s0.z > pm ? 1.f : 0.f) + (s0.w > pm ? 1.f : 0.f) +
              (s1.x > pm ? 1.f : 0.f) + (s1.y > pm ? 1.f : 0.f) +
              (s1.z > pm ? 1.f : 0.f) + (s1.w > pm ? 1.f : 0.f);
#pragma unroll
    for (int m = 1; m < 16; m <<= 1) {
      s += __shfl_xor(s, m, 64);
      s2 += __shfl_xor(s2, m, 64);
      c += __shfl_xor(c, m, 64);
      mx = fmaxf(mx, __shfl_xor(mx, m, 64));
    }
    if ((tid & 15) == 0) {
      f32x4 p = {s, s2, mx, c};
      *(f32x4*)&partials[((size_t)(mt * 16 + srow) * 512 + blk) * 4] = p;
    }
  };

  uint4 afA[8], afB[8];
  load_af(afA, 0);
#pragma unroll 1
  for (int mt2 = 0; mt2 < 16; mt2++) {
    int mt = mt2 * 2;
    load_af(afB, mt + 1);
    body(afA, mt);
    if (mt2 < 15) load_af(afA, mt + 2);
    body(afB, mt + 1);
  }
}

// combine 512 per-block partials per row -> score[:, 0:4]
__global__ __launch_bounds__(256) void kreduce(const float* __restrict__ partials,
                                               const float* __restrict__ spos,
                                               float* __restrict__ out) {
  int b = blockIdx.x, tid = threadIdx.x;
  const f32x4* p = (const f32x4*)(partials + (size_t)b * 2048);
  float s = 0.f, s2 = 0.f, mx = -2.f, c = 0.f;
#pragma unroll
  for (int i = 0; i < 2; i++) {
    f32x4 v = p[tid + i * 256];
    s += v.x; s2 += v.y; mx = fmaxf(mx, v.z); c += v.w;
  }
#pragma unroll
  for (int m = 1; m < 64; m <<= 1) {
    s += __shfl_xor(s, m, 64);
    s2 += __shfl_xor(s2, m, 64);
    c += __shfl_xor(c, m, 64);
    mx = fmaxf(mx, __shfl_xor(mx, m, 64));
  }
  __shared__ float red[4][4];
  int w = tid >> 6, l = tid & 63;
  if (l == 0) { red[w][0] = s; red[w][1] = s2; red[w][2] = c; red[w][3] = mx; }
  __syncthreads();
  if (tid == 0) {
    float S = 0, S2 = 0, C = 0, M = -2.f;
    for (int i = 0; i < 4; i++) {
      S += red[i][0]; S2 += red[i][1]; C += red[i][2]; M = fmaxf(M, red[i][3]);
    }
    float mean = S / (float)NKQ;
    float var = (S2 - S * S / (float)NKQ) / (float)(NKQ - 1);  // ddof=1
    float cp = 0.f;
    for (int j = 0; j < 3; j++) cp += (M > spos[b * 3 + j]) ? 1.f : 0.f;
    float* scr = out + OFF_SCORE + (size_t)b * 7;
    scr[0] = mean; scr[1] = var; scr[2] = C; scr[3] = cp;
  }
}

extern "C" void kernel_launch(void* const* d_in, const int* in_sizes, int n_in,
                              void* d_out, int out_size, void* d_ws, size_t ws_size,
                              hipStream_t stream) {
  const float* query = (const float*)d_in[0];
  const float* key_emb = (const float*)d_in[1];
  const float* queue = (const float*)d_in[2];
  float* out = (float*)d_out;
  _Float16* qf16 = (_Float16*)d_ws;
  float* qf32 = (float*)((char*)d_ws + 262144);
  float* posmin = (float*)((char*)d_ws + 786432);
  float* spos = (float*)((char*)d_ws + 788480);
  float* partials = (float*)((char*)d_ws + 1048576);

  kprep<<<2048, 256, 0, stream>>>(query, key_emb, out, qf16, qf32);
  kpos<<<512, 64, 0, stream>>>(qf32, out, posmin, spos);
  kgemm<<<512, 256, 0, stream>>>(queue, qf16, posmin, out, partials);
  kreduce<<<512, 256, 0, stream>>>(partials, spos, out);
}